// Round 2
// baseline (69.774 us; speedup 1.0000x reference)
//
#include <hip/hip_runtime.h>

#define KQ 128
#define NB 128
#define MC 385            // 3K + 1 constraints
#define ITERS 25
#define SIGMA 0.1

__device__ __forceinline__ double wsumd(double v) {
#pragma unroll
    for (int o = 32; o > 0; o >>= 1) v += __shfl_xor(v, o, 64);
    return v;
}
__device__ __forceinline__ double wmind(double v) {
#pragma unroll
    for (int o = 32; o > 0; o >>= 1) v = fmin(v, __shfl_xor(v, o, 64));
    return v;
}
__device__ __forceinline__ double ratiod(double x, double dx) {
    return dx < 0.0 ? -x / dx : 1e30;
}

// One 64-lane wave per batch element. K=128 -> each lane owns quantile
// indices (lane, lane+64). All state in registers (f64 internally).
//
// Variables: z0 (uniform scalar), zb[i], zh[i].
// Constraints (rows of G):
//   c1[i]: -z0 - zb[i] <= -d[i]        (i = 0..K-1)
//   c2[i]:  z0 - zh[i] <=  d[i]
//   c3  : -z <= 0  elementwise: c30 (-z0<=0, uniform), c3b[i], c3h[i]
//
// Reduced KKT  (diag(q) + G' D G) dz = rhs  is an ARROW matrix:
//   A(0,0)       = q0 + sum(d1) + sum(d2) + d30
//   A(0,b_i)     = d1[i]        A(0,h_i) = -d2[i]
//   A(b_i,b_i)   = qb[i] + d1[i] + d3b[i]
//   A(h_i,h_i)   = qh[i] + d2[i] + d3h[i]
// Solved exactly via Schur complement on (0,0), with the denominator in
// the cancellation-free form  q0 + d30 + sum d*(q+d3)/c  (all terms > 0).
__global__ __launch_bounds__(64) void newsvendor_pdip(
    const float* __restrict__ y,   // (B,K)
    const float* __restrict__ Qd,  // (N)
    const float* __restrict__ pv,  // (N)
    const float* __restrict__ h,   // (M)
    float* __restrict__ out)       // (B)
{
    const int b = blockIdx.x;
    const int lane = threadIdx.x;
    const int i0 = lane, i1 = lane + 64;

    const double y0 = (double)y[b * KQ + i0], y1 = (double)y[b * KQ + i1];
    const double d0 = -(double)h[i0], d1v = -(double)h[i1];   // h[0:K] = -d
    const double q0 = (double)Qd[0], p0c = (double)pv[0];
    const double qb0 = (double)Qd[1 + i0] * y0,      qb1 = (double)Qd[1 + i1] * y1;
    const double qh0 = (double)Qd[1 + KQ + i0] * y0, qh1 = (double)Qd[1 + KQ + i1] * y1;
    const double pb0 = (double)pv[1 + i0] * y0,      pb1 = (double)pv[1 + i1] * y1;
    const double ph0 = (double)pv[1 + KQ + i0] * y0, ph1 = (double)pv[1 + KQ + i1] * y1;

    // state
    double z0 = 0, zb0 = 0, zb1 = 0, zh0 = 0, zh1 = 0;
    double s1_0 = 1, s1_1 = 1, s2_0 = 1, s2_1 = 1;
    double s3b0 = 1, s3b1 = 1, s3h0 = 1, s3h1 = 1, s30 = 1;
    double l1_0 = 1, l1_1 = 1, l2_0 = 1, l2_1 = 1;
    double l3b0 = 1, l3b1 = 1, l3h0 = 1, l3h1 = 1, l30 = 1;

    for (int it = 0; it < ITERS; ++it) {
        // D = lam/s
        const double di1_0 = l1_0 / s1_0, di1_1 = l1_1 / s1_1;
        const double di2_0 = l2_0 / s2_0, di2_1 = l2_1 / s2_1;
        const double di3b0 = l3b0 / s3b0, di3b1 = l3b1 / s3b1;
        const double di3h0 = l3h0 / s3h0, di3h1 = l3h1 / s3h1;
        const double di30 = l30 / s30;

        // r_prim = Gz + s - h
        const double rp1_0 = -z0 - zb0 + s1_0 + d0;
        const double rp1_1 = -z0 - zb1 + s1_1 + d1v;
        const double rp2_0 =  z0 - zh0 + s2_0 - d0;
        const double rp2_1 =  z0 - zh1 + s2_1 - d1v;
        const double rp3b0 = -zb0 + s3b0, rp3b1 = -zb1 + s3b1;
        const double rp3h0 = -zh0 + s3h0, rp3h1 = -zh1 + s3h1;
        const double rp30 = -z0 + s30;

        // mu = mean(s*lam);  smu = SIGMA*mu
        double musum = s1_0 * l1_0 + s1_1 * l1_1 + s2_0 * l2_0 + s2_1 * l2_1
                     + s3b0 * l3b0 + s3b1 * l3b1 + s3h0 * l3h0 + s3h1 * l3h1;
        musum = wsumd(musum) + s30 * l30;
        const double smu = SIGMA * musum / (double)MC;

        // w = lam + (D r_prim + smu/s - lam) = D*r_prim + smu/s
        const double w1_0 = di1_0 * rp1_0 + smu / s1_0;
        const double w1_1 = di1_1 * rp1_1 + smu / s1_1;
        const double w2_0 = di2_0 * rp2_0 + smu / s2_0;
        const double w2_1 = di2_1 * rp2_1 + smu / s2_1;
        const double w3b0 = di3b0 * rp3b0 + smu / s3b0;
        const double w3b1 = di3b1 * rp3b1 + smu / s3b1;
        const double w3h0 = di3h0 * rp3h0 + smu / s3h0;
        const double w3h1 = di3h1 * rp3h1 + smu / s3h1;
        const double w30 = di30 * rp30 + smu / s30;

        // rhs_j = -(q_j z_j + p_j + (w@G)_j); columns of G have <=2 nz (+-1)
        const double rhsb0 = -(qb0 * zb0 + pb0) + w1_0 + w3b0;
        const double rhsb1 = -(qb1 * zb1 + pb1) + w1_1 + w3b1;
        const double rhsh0 = -(qh0 * zh0 + ph0) + w2_0 + w3h0;
        const double rhsh1 = -(qh1 * zh1 + ph1) + w2_1 + w3h1;

        // arrow diag + off-diag
        const double cb0 = qb0 + di1_0 + di3b0, cb1 = qb1 + di1_1 + di3b1;
        const double ch0 = qh0 + di2_0 + di3h0, ch1 = qh1 + di2_1 + di3h1;
        // Schur pieces, per-lane then one packed reduction:
        //  colsum part of rhs0:  -w1 + w2  (minus w30 added after)
        //  sbr = sum b_j rhs_j / c_j   (b_b = d1, b_h = -d2)
        //  den = q0 + d30 + sum d*(q+d3)/c   (cancellation-free Schur denom)
        double colsum_l = -w1_0 - w1_1 + w2_0 + w2_1;
        double sbr_l = di1_0 * rhsb0 / cb0 + di1_1 * rhsb1 / cb1
                     - di2_0 * rhsh0 / ch0 - di2_1 * rhsh1 / ch1;
        double den_l = di1_0 * (qb0 + di3b0) / cb0 + di1_1 * (qb1 + di3b1) / cb1
                     + di2_0 * (qh0 + di3h0) / ch0 + di2_1 * (qh1 + di3h1) / ch1;
        const double colsum = wsumd(colsum_l) - w30;
        const double sbr = wsumd(sbr_l);
        const double den = q0 + di30 + wsumd(den_l);

        const double rhs0 = -(q0 * z0 + p0c + colsum);
        const double dz0 = (rhs0 - sbr) / den;
        const double dzb0 = (rhsb0 - di1_0 * dz0) / cb0;
        const double dzb1 = (rhsb1 - di1_1 * dz0) / cb1;
        const double dzh0 = (rhsh0 + di2_0 * dz0) / ch0;
        const double dzh1 = (rhsh1 + di2_1 * dz0) / ch1;

        // Gdz
        const double g1_0 = -dz0 - dzb0, g1_1 = -dz0 - dzb1;
        const double g2_0 =  dz0 - dzh0, g2_1 =  dz0 - dzh1;
        const double g3b0 = -dzb0, g3b1 = -dzb1;
        const double g3h0 = -dzh0, g3h1 = -dzh1;
        const double g30 = -dz0;

        // ds = -r_prim - Gdz ; dlam = -D*ds + smu/s - lam
        const double ds1_0 = -rp1_0 - g1_0, ds1_1 = -rp1_1 - g1_1;
        const double ds2_0 = -rp2_0 - g2_0, ds2_1 = -rp2_1 - g2_1;
        const double ds3b0 = -rp3b0 - g3b0, ds3b1 = -rp3b1 - g3b1;
        const double ds3h0 = -rp3h0 - g3h0, ds3h1 = -rp3h1 - g3h1;
        const double ds30 = -rp30 - g30;
        const double dl1_0 = -di1_0 * ds1_0 + smu / s1_0 - l1_0;
        const double dl1_1 = -di1_1 * ds1_1 + smu / s1_1 - l1_1;
        const double dl2_0 = -di2_0 * ds2_0 + smu / s2_0 - l2_0;
        const double dl2_1 = -di2_1 * ds2_1 + smu / s2_1 - l2_1;
        const double dl3b0 = -di3b0 * ds3b0 + smu / s3b0 - l3b0;
        const double dl3b1 = -di3b1 * ds3b1 + smu / s3b1 - l3b1;
        const double dl3h0 = -di3h0 * ds3h0 + smu / s3h0 - l3h0;
        const double dl3h1 = -di3h1 * ds3h1 + smu / s3h1 - l3h1;
        const double dl30 = -di30 * ds30 + smu / s30 - l30;

        // fraction-to-boundary: min over all -s/ds, -lam/dlam (neg dirs only)
        double am = fmin(fmin(ratiod(s1_0, ds1_0), ratiod(s1_1, ds1_1)),
                         fmin(ratiod(s2_0, ds2_0), ratiod(s2_1, ds2_1)));
        am = fmin(am, fmin(fmin(ratiod(s3b0, ds3b0), ratiod(s3b1, ds3b1)),
                           fmin(ratiod(s3h0, ds3h0), ratiod(s3h1, ds3h1))));
        am = fmin(am, fmin(fmin(ratiod(l1_0, dl1_0), ratiod(l1_1, dl1_1)),
                           fmin(ratiod(l2_0, dl2_0), ratiod(l2_1, dl2_1))));
        am = fmin(am, fmin(fmin(ratiod(l3b0, dl3b0), ratiod(l3b1, dl3b1)),
                           fmin(ratiod(l3h0, dl3h0), ratiod(l3h1, dl3h1))));
        am = wmind(am);
        am = fmin(am, fmin(ratiod(s30, ds30), ratiod(l30, dl30)));
        const double alpha = fmin(1.0, 0.99 * am);

        // updates
        z0 += alpha * dz0;
        zb0 += alpha * dzb0; zb1 += alpha * dzb1;
        zh0 += alpha * dzh0; zh1 += alpha * dzh1;
        s1_0 += alpha * ds1_0; s1_1 += alpha * ds1_1;
        s2_0 += alpha * ds2_0; s2_1 += alpha * ds2_1;
        s3b0 += alpha * ds3b0; s3b1 += alpha * ds3b1;
        s3h0 += alpha * ds3h0; s3h1 += alpha * ds3h1;
        s30 += alpha * ds30;
        l1_0 += alpha * dl1_0; l1_1 += alpha * dl1_1;
        l2_0 += alpha * dl2_0; l2_1 += alpha * dl2_1;
        l3b0 += alpha * dl3b0; l3b1 += alpha * dl3b1;
        l3h0 += alpha * dl3h0; l3h1 += alpha * dl3h1;
        l30 += alpha * dl30;
    }

    if (lane == 0) out[b] = (float)z0;
}

extern "C" void kernel_launch(void* const* d_in, const int* in_sizes, int n_in,
                              void* d_out, int out_size, void* d_ws, size_t ws_size,
                              hipStream_t stream) {
    const float* y  = (const float*)d_in[0];
    const float* Qd = (const float*)d_in[1];
    const float* pv = (const float*)d_in[2];
    // d_in[3] = G (implicit structure, unused)
    const float* h  = (const float*)d_in[4];
    float* out = (float*)d_out;

    newsvendor_pdip<<<NB, 64, 0, stream>>>(y, Qd, pv, h, out);
}

// Round 3
// 43.331 us; speedup vs baseline: 1.6103x; 1.6103x over previous
//
#include <hip/hip_runtime.h>

#define KQ 128
#define NB 128
#define ITERS 25
#define SMU_SCALE (0.1 / 385.0)   // SIGMA / M

// fast f64 reciprocal: v_rcp_f64 seed + 2 Newton steps (~1 ulp).
// Two steps converge to full f64 even from a float-precision seed.
__device__ __forceinline__ double frcp(double x) {
#if __has_builtin(__builtin_amdgcn_rcp)
    double r = __builtin_amdgcn_rcp(x);
#else
    double r = 1.0 / x;
#endif
    r = r * __builtin_fma(-x, r, 2.0);
    r = r * __builtin_fma(-x, r, 2.0);
    return r;
}

// one fused 6-value f64 butterfly reduction (independent chains pipeline)
__device__ __forceinline__ void wsum6(double& a, double& b, double& c,
                                      double& d, double& e, double& f) {
#pragma unroll
    for (int o = 32; o > 0; o >>= 1) {
        a += __shfl_xor(a, o, 64);
        b += __shfl_xor(b, o, 64);
        c += __shfl_xor(c, o, 64);
        d += __shfl_xor(d, o, 64);
        e += __shfl_xor(e, o, 64);
        f += __shfl_xor(f, o, 64);
    }
}

__device__ __forceinline__ double wmaxd(double v) {
#pragma unroll
    for (int o = 32; o > 0; o >>= 1) v = fmax(v, __shfl_xor(v, o, 64));
    return v;
}

// step-length term: contributes -dx/x when dx<0 (x>0), else 0; max-reduced.
__device__ __forceinline__ double rterm(double dx, double rx) {
    return dx < 0.0 ? -dx * rx : 0.0;
}

// One 64-lane wave per batch element; lane owns quantile indices (lane, lane+64).
// All state in registers (f64). Reduced KKT (diag(q)+G'DG) is an arrow matrix,
// solved exactly via Schur complement on the (0,0) entry with a
// cancellation-free denominator. See R1 for the constraint/variable layout.
__global__ __launch_bounds__(64) void newsvendor_pdip(
    const float* __restrict__ y,   // (B,K)
    const float* __restrict__ Qd,  // (N)
    const float* __restrict__ pv,  // (N)
    const float* __restrict__ h,   // (M)
    float* __restrict__ out)       // (B)
{
    const int b = blockIdx.x;
    const int lane = threadIdx.x;
    const int i0 = lane, i1 = lane + 64;

    const double y0 = (double)y[b * KQ + i0], y1 = (double)y[b * KQ + i1];
    const double d0 = -(double)h[i0], d1v = -(double)h[i1];   // h[0:K] = -d
    const double q0 = (double)Qd[0], p0c = (double)pv[0];
    const double qb0 = (double)Qd[1 + i0] * y0,      qb1 = (double)Qd[1 + i1] * y1;
    const double qh0 = (double)Qd[1 + KQ + i0] * y0, qh1 = (double)Qd[1 + KQ + i1] * y1;
    const double pb0 = (double)pv[1 + i0] * y0,      pb1 = (double)pv[1 + i1] * y1;
    const double ph0 = (double)pv[1 + KQ + i0] * y0, ph1 = (double)pv[1 + KQ + i1] * y1;

    // state
    double z0 = 0, zb0 = 0, zb1 = 0, zh0 = 0, zh1 = 0;
    double s1_0 = 1, s1_1 = 1, s2_0 = 1, s2_1 = 1;
    double s3b0 = 1, s3b1 = 1, s3h0 = 1, s3h1 = 1, s30 = 1;
    double l1_0 = 1, l1_1 = 1, l2_0 = 1, l2_1 = 1;
    double l3b0 = 1, l3b1 = 1, l3h0 = 1, l3h1 = 1, l30 = 1;

#pragma unroll 1
    for (int it = 0; it < ITERS; ++it) {
        // ---- reciprocals (all independent -> pipelined) ----
        const double rs1_0 = frcp(s1_0), rs1_1 = frcp(s1_1);
        const double rs2_0 = frcp(s2_0), rs2_1 = frcp(s2_1);
        const double rs3b0 = frcp(s3b0), rs3b1 = frcp(s3b1);
        const double rs3h0 = frcp(s3h0), rs3h1 = frcp(s3h1);
        const double rs30 = frcp(s30);
        const double rl1_0 = frcp(l1_0), rl1_1 = frcp(l1_1);
        const double rl2_0 = frcp(l2_0), rl2_1 = frcp(l2_1);
        const double rl3b0 = frcp(l3b0), rl3b1 = frcp(l3b1);
        const double rl3h0 = frcp(l3h0), rl3h1 = frcp(l3h1);
        const double rl30 = frcp(l30);

        // D = lam/s
        const double di1_0 = l1_0 * rs1_0, di1_1 = l1_1 * rs1_1;
        const double di2_0 = l2_0 * rs2_0, di2_1 = l2_1 * rs2_1;
        const double di3b0 = l3b0 * rs3b0, di3b1 = l3b1 * rs3b1;
        const double di3h0 = l3h0 * rs3h0, di3h1 = l3h1 * rs3h1;
        const double di30 = l30 * rs30;

        // r_prim = Gz + s - h
        const double rp1_0 = -z0 - zb0 + s1_0 + d0;
        const double rp1_1 = -z0 - zb1 + s1_1 + d1v;
        const double rp2_0 =  z0 - zh0 + s2_0 - d0;
        const double rp2_1 =  z0 - zh1 + s2_1 - d1v;
        const double rp3b0 = -zb0 + s3b0, rp3b1 = -zb1 + s3b1;
        const double rp3h0 = -zh0 + s3h0, rp3h1 = -zh1 + s3h1;
        const double rp30 = -z0 + s30;

        // w = D*r_prim + smu/s, split as wb + smu*rs (linear in smu)
        const double wb1_0 = di1_0 * rp1_0, wb1_1 = di1_1 * rp1_1;
        const double wb2_0 = di2_0 * rp2_0, wb2_1 = di2_1 * rp2_1;
        const double wb3b0 = di3b0 * rp3b0, wb3b1 = di3b1 * rp3b1;
        const double wb3h0 = di3h0 * rp3h0, wb3h1 = di3h1 * rp3h1;

        // rhs_j = -(q_j z_j + p_j) + (col sums of w), split base/coef
        const double rhsb0_b = wb1_0 + wb3b0 - (qb0 * zb0 + pb0);
        const double rhsb1_b = wb1_1 + wb3b1 - (qb1 * zb1 + pb1);
        const double rhsh0_b = wb2_0 + wb3h0 - (qh0 * zh0 + ph0);
        const double rhsh1_b = wb2_1 + wb3h1 - (qh1 * zh1 + ph1);
        const double rhsb0_c = rs1_0 + rs3b0, rhsb1_c = rs1_1 + rs3b1;
        const double rhsh0_c = rs2_0 + rs3h0, rhsh1_c = rs2_1 + rs3h1;

        // arrow diagonal c = q + d1 + d3 (t = q + d3 kept for cancel-free den)
        const double tb0 = qb0 + di3b0, tb1 = qb1 + di3b1;
        const double th0 = qh0 + di3h0, th1 = qh1 + di3h1;
        const double cb0 = tb0 + di1_0, cb1 = tb1 + di1_1;
        const double ch0 = th0 + di2_0, ch1 = th1 + di2_1;
        const double rcb0 = frcp(cb0), rcb1 = frcp(cb1);
        const double rch0 = frcp(ch0), rch1 = frcp(ch1);
        const double eb0 = di1_0 * rcb0, eb1 = di1_1 * rcb1;   // b/c ratios
        const double eh0 = di2_0 * rch0, eh1 = di2_1 * rch1;

        // fused reduction payloads
        double mus = s1_0 * l1_0 + s1_1 * l1_1 + s2_0 * l2_0 + s2_1 * l2_1
                   + s3b0 * l3b0 + s3b1 * l3b1 + s3h0 * l3h0 + s3h1 * l3h1;
        double cs_b = -wb1_0 - wb1_1 + wb2_0 + wb2_1;          // (w@G)_0 base
        double cs_c = -rs1_0 - rs1_1 + rs2_0 + rs2_1;          // (w@G)_0 coef
        double sbr_b = eb0 * rhsb0_b + eb1 * rhsb1_b - eh0 * rhsh0_b - eh1 * rhsh1_b;
        double sbr_c = eb0 * rhsb0_c + eb1 * rhsb1_c - eh0 * rhsh0_c - eh1 * rhsh1_c;
        double den_s = eb0 * tb0 + eb1 * tb1 + eh0 * th0 + eh1 * th1;

        wsum6(mus, cs_b, cs_c, sbr_b, sbr_c, den_s);

        // scalar (uniform) pieces
        mus += s30 * l30;
        const double smu = SMU_SCALE * mus;
        const double wb30 = di30 * rp30;
        const double w30 = wb30 + smu * rs30;
        const double colsum = cs_b + smu * cs_c - w30;
        const double rhs0 = -(q0 * z0 + p0c + colsum);
        const double sbr = sbr_b + smu * sbr_c;
        const double den = q0 + di30 + den_s;     // all terms positive
        const double dz0 = (rhs0 - sbr) * frcp(den);

        // back-substitution
        const double rhsb0 = rhsb0_b + smu * rhsb0_c;
        const double rhsb1 = rhsb1_b + smu * rhsb1_c;
        const double rhsh0 = rhsh0_b + smu * rhsh0_c;
        const double rhsh1 = rhsh1_b + smu * rhsh1_c;
        const double dzb0 = (rhsb0 - di1_0 * dz0) * rcb0;
        const double dzb1 = (rhsb1 - di1_1 * dz0) * rcb1;
        const double dzh0 = (rhsh0 + di2_0 * dz0) * rch0;
        const double dzh1 = (rhsh1 + di2_1 * dz0) * rch1;

        // ds = -r_prim - Gdz
        const double ds1_0 = dz0 + dzb0 - rp1_0, ds1_1 = dz0 + dzb1 - rp1_1;
        const double ds2_0 = dzh0 - dz0 - rp2_0, ds2_1 = dzh1 - dz0 - rp2_1;
        const double ds3b0 = dzb0 - rp3b0, ds3b1 = dzb1 - rp3b1;
        const double ds3h0 = dzh0 - rp3h0, ds3h1 = dzh1 - rp3h1;
        const double ds30 = dz0 - rp30;

        // dlam = -D*ds + smu/s - lam
        const double dl1_0 = smu * rs1_0 - l1_0 - di1_0 * ds1_0;
        const double dl1_1 = smu * rs1_1 - l1_1 - di1_1 * ds1_1;
        const double dl2_0 = smu * rs2_0 - l2_0 - di2_0 * ds2_0;
        const double dl2_1 = smu * rs2_1 - l2_1 - di2_1 * ds2_1;
        const double dl3b0 = smu * rs3b0 - l3b0 - di3b0 * ds3b0;
        const double dl3b1 = smu * rs3b1 - l3b1 - di3b1 * ds3b1;
        const double dl3h0 = smu * rs3h0 - l3h0 - di3h0 * ds3h0;
        const double dl3h1 = smu * rs3h1 - l3h1 - di3h1 * ds3h1;
        const double dl30 = smu * rs30 - l30 - di30 * ds30;

        // fraction-to-boundary via max of -dx/x (multiplies, no divides)
        double mr = fmax(fmax(rterm(ds1_0, rs1_0), rterm(ds1_1, rs1_1)),
                         fmax(rterm(ds2_0, rs2_0), rterm(ds2_1, rs2_1)));
        mr = fmax(mr, fmax(fmax(rterm(ds3b0, rs3b0), rterm(ds3b1, rs3b1)),
                           fmax(rterm(ds3h0, rs3h0), rterm(ds3h1, rs3h1))));
        mr = fmax(mr, fmax(fmax(rterm(dl1_0, rl1_0), rterm(dl1_1, rl1_1)),
                           fmax(rterm(dl2_0, rl2_0), rterm(dl2_1, rl2_1))));
        mr = fmax(mr, fmax(fmax(rterm(dl3b0, rl3b0), rterm(dl3b1, rl3b1)),
                           fmax(rterm(dl3h0, rl3h0), rterm(dl3h1, rl3h1))));
        mr = fmax(mr, fmax(rterm(ds30, rs30), rterm(dl30, rl30)));
        mr = wmaxd(mr);
        const double alpha = fmin(1.0, 0.99 / mr);   // mr==0 -> inf -> 1

        // updates
        z0 += alpha * dz0;
        zb0 += alpha * dzb0; zb1 += alpha * dzb1;
        zh0 += alpha * dzh0; zh1 += alpha * dzh1;
        s1_0 += alpha * ds1_0; s1_1 += alpha * ds1_1;
        s2_0 += alpha * ds2_0; s2_1 += alpha * ds2_1;
        s3b0 += alpha * ds3b0; s3b1 += alpha * ds3b1;
        s3h0 += alpha * ds3h0; s3h1 += alpha * ds3h1;
        s30 += alpha * ds30;
        l1_0 += alpha * dl1_0; l1_1 += alpha * dl1_1;
        l2_0 += alpha * dl2_0; l2_1 += alpha * dl2_1;
        l3b0 += alpha * dl3b0; l3b1 += alpha * dl3b1;
        l3h0 += alpha * dl3h0; l3h1 += alpha * dl3h1;
        l30 += alpha * dl30;
    }

    if (lane == 0) out[b] = (float)z0;
}

extern "C" void kernel_launch(void* const* d_in, const int* in_sizes, int n_in,
                              void* d_out, int out_size, void* d_ws, size_t ws_size,
                              hipStream_t stream) {
    const float* y  = (const float*)d_in[0];
    const float* Qd = (const float*)d_in[1];
    const float* pv = (const float*)d_in[2];
    // d_in[3] = G (implicit structure, unused)
    const float* h  = (const float*)d_in[4];
    float* out = (float*)d_out;

    newsvendor_pdip<<<NB, 64, 0, stream>>>(y, Qd, pv, h, out);
}

// Round 4
// 26.577 us; speedup vs baseline: 2.6253x; 1.6304x over previous
//
#include <hip/hip_runtime.h>

#define KQ 128
#define NB 128
#define ITERS 25
#define SMU_SCALE (0.1 / 385.0)   // SIGMA / M

// fast f64 reciprocal: v_rcp_f64 seed + 2 Newton steps (~1 ulp).
__device__ __forceinline__ double frcp(double x) {
#if __has_builtin(__builtin_amdgcn_rcp)
    double r = __builtin_amdgcn_rcp(x);
#else
    double r = 1.0 / x;
#endif
    r = r * __builtin_fma(-x, r, 2.0);
    r = r * __builtin_fma(-x, r, 2.0);
    return r;
}
__device__ __forceinline__ float frcpf(float x) {
#if __has_builtin(__builtin_amdgcn_rcpf)
    return __builtin_amdgcn_rcpf(x);
#else
    return 1.0f / x;
#endif
}

// DPP cross-lane move (zero-fill OOB). CTRL: 0xB1 quad xor1, 0x4E quad xor2,
// 0x141 row_half_mirror, 0x140 row_mirror, 0x142 row_bcast15, 0x143 row_bcast31.
template <int CTRL>
__device__ __forceinline__ double dpp_d(double v) {
    union { double d; int i[2]; } u, r;
    u.d = v;
    r.i[0] = __builtin_amdgcn_update_dpp(0, u.i[0], CTRL, 0xf, 0xf, true);
    r.i[1] = __builtin_amdgcn_update_dpp(0, u.i[1], CTRL, 0xf, 0xf, true);
    return r.d;
}
template <int CTRL>
__device__ __forceinline__ float dpp_f(float v) {
    union { float f; int i; } u, r;
    u.f = v;
    r.i = __builtin_amdgcn_update_dpp(0, u.i, CTRL, 0xf, 0xf, true);
    return r.f;
}
__device__ __forceinline__ double rdl63_d(double v) {
    union { double d; int i[2]; } u, r;
    u.d = v;
    r.i[0] = __builtin_amdgcn_readlane(u.i[0], 63);
    r.i[1] = __builtin_amdgcn_readlane(u.i[1], 63);
    return r.d;
}
__device__ __forceinline__ float rdl63_f(float v) {
    union { float f; int i; } u, r;
    u.f = v;
    r.i = __builtin_amdgcn_readlane(u.i, 63);
    return r.f;
}

// One 64-lane wave per batch element; lane owns quantile indices (lane, lane+64).
// All solve-path state in f64 registers; step-length path in f32.
// Reduced KKT (diag(q)+G'DG) is an arrow matrix solved exactly via Schur
// complement on the (0,0) entry with a cancellation-free denominator.
__global__ __launch_bounds__(64) void newsvendor_pdip(
    const float* __restrict__ y,   // (B,K)
    const float* __restrict__ Qd,  // (N)
    const float* __restrict__ pv,  // (N)
    const float* __restrict__ h,   // (M)
    float* __restrict__ out)       // (B)
{
    const int b = blockIdx.x;
    const int lane = threadIdx.x;
    const int i0 = lane, i1 = lane + 64;

    const double y0 = (double)y[b * KQ + i0], y1 = (double)y[b * KQ + i1];
    const double d0 = -(double)h[i0], d1v = -(double)h[i1];   // h[0:K] = -d
    const double q0 = (double)Qd[0], p0c = (double)pv[0];
    const double qb0 = (double)Qd[1 + i0] * y0,      qb1 = (double)Qd[1 + i1] * y1;
    const double qh0 = (double)Qd[1 + KQ + i0] * y0, qh1 = (double)Qd[1 + KQ + i1] * y1;
    const double pb0 = (double)pv[1 + i0] * y0,      pb1 = (double)pv[1 + i1] * y1;
    const double ph0 = (double)pv[1 + KQ + i0] * y0, ph1 = (double)pv[1 + KQ + i1] * y1;

    // state
    double z0 = 0, zb0 = 0, zb1 = 0, zh0 = 0, zh1 = 0;
    double s1_0 = 1, s1_1 = 1, s2_0 = 1, s2_1 = 1;
    double s3b0 = 1, s3b1 = 1, s3h0 = 1, s3h1 = 1, s30 = 1;
    double l1_0 = 1, l1_1 = 1, l2_0 = 1, l2_1 = 1;
    double l3b0 = 1, l3b1 = 1, l3h0 = 1, l3h1 = 1, l30 = 1;

#pragma unroll 1
    for (int it = 0; it < ITERS; ++it) {
        // ---- f64 reciprocals of slacks (solve path) ----
        const double rs1_0 = frcp(s1_0), rs1_1 = frcp(s1_1);
        const double rs2_0 = frcp(s2_0), rs2_1 = frcp(s2_1);
        const double rs3b0 = frcp(s3b0), rs3b1 = frcp(s3b1);
        const double rs3h0 = frcp(s3h0), rs3h1 = frcp(s3h1);
        const double rs30 = frcp(s30);

        // D = lam/s
        const double di1_0 = l1_0 * rs1_0, di1_1 = l1_1 * rs1_1;
        const double di2_0 = l2_0 * rs2_0, di2_1 = l2_1 * rs2_1;
        const double di3b0 = l3b0 * rs3b0, di3b1 = l3b1 * rs3b1;
        const double di3h0 = l3h0 * rs3h0, di3h1 = l3h1 * rs3h1;
        const double di30 = l30 * rs30;

        // r_prim = Gz + s - h
        const double rp1_0 = -z0 - zb0 + s1_0 + d0;
        const double rp1_1 = -z0 - zb1 + s1_1 + d1v;
        const double rp2_0 =  z0 - zh0 + s2_0 - d0;
        const double rp2_1 =  z0 - zh1 + s2_1 - d1v;
        const double rp3b0 = -zb0 + s3b0, rp3b1 = -zb1 + s3b1;
        const double rp3h0 = -zh0 + s3h0, rp3h1 = -zh1 + s3h1;
        const double rp30 = -z0 + s30;

        // w-base = D*r_prim (w = wb + smu/s, linear in smu)
        const double wb1_0 = di1_0 * rp1_0, wb1_1 = di1_1 * rp1_1;
        const double wb2_0 = di2_0 * rp2_0, wb2_1 = di2_1 * rp2_1;

        // rhs split base/coef
        const double rhsb0_b = wb1_0 + di3b0 * rp3b0 - (qb0 * zb0 + pb0);
        const double rhsb1_b = wb1_1 + di3b1 * rp3b1 - (qb1 * zb1 + pb1);
        const double rhsh0_b = wb2_0 + di3h0 * rp3h0 - (qh0 * zh0 + ph0);
        const double rhsh1_b = wb2_1 + di3h1 * rp3h1 - (qh1 * zh1 + ph1);
        const double rhsb0_c = rs1_0 + rs3b0, rhsb1_c = rs1_1 + rs3b1;
        const double rhsh0_c = rs2_0 + rs3h0, rhsh1_c = rs2_1 + rs3h1;

        // arrow diagonal c = t + d1/d2,  t = q + d3 (cancel-free den pieces)
        const double tb0 = qb0 + di3b0, tb1 = qb1 + di3b1;
        const double th0 = qh0 + di3h0, th1 = qh1 + di3h1;
        const double cb0 = tb0 + di1_0, cb1 = tb1 + di1_1;
        const double ch0 = th0 + di2_0, ch1 = th1 + di2_1;
        const double rcb0 = frcp(cb0), rcb1 = frcp(cb1);
        const double rch0 = frcp(ch0), rch1 = frcp(ch1);
        const double eb0 = di1_0 * rcb0, eb1 = di1_1 * rcb1;
        const double eh0 = di2_0 * rch0, eh1 = di2_1 * rch1;

        // fused reduction payloads:
        // P = (w@G)_0 base + sbr base ; Q = same, smu-coefs ; den = Schur sum
        double P = -wb1_0 - wb1_1 + wb2_0 + wb2_1
                 + eb0 * rhsb0_b + eb1 * rhsb1_b - eh0 * rhsh0_b - eh1 * rhsh1_b;
        double Q = -rs1_0 - rs1_1 + rs2_0 + rs2_1
                 + eb0 * rhsb0_c + eb1 * rhsb1_c - eh0 * rhsh0_c - eh1 * rhsh1_c;
        double den = eb0 * tb0 + eb1 * tb1 + eh0 * th0 + eh1 * th1;
        float musf = (float)(s1_0 * l1_0 + s1_1 * l1_1 + s2_0 * l2_0 + s2_1 * l2_1
                   + s3b0 * l3b0 + s3b1 * l3b1 + s3h0 * l3h0 + s3h1 * l3h1);

#define SUM_STEP(C) \
        P += dpp_d<C>(P); Q += dpp_d<C>(Q); den += dpp_d<C>(den); musf += dpp_f<C>(musf);
        SUM_STEP(0xB1) SUM_STEP(0x4E) SUM_STEP(0x141)
        SUM_STEP(0x140) SUM_STEP(0x142) SUM_STEP(0x143)
#undef SUM_STEP
        const double Pt = rdl63_d(P);
        const double Qt = rdl63_d(Q);
        const double dent = rdl63_d(den);
        const double must = (double)rdl63_f(musf) + s30 * l30;

        // scalar (wave-uniform) pieces
        const double smu = SMU_SCALE * must;
        const double wb30 = di30 * rp30;
        const double w30 = wb30 + smu * rs30;
        const double num = -(q0 * z0 + p0c) - Pt - smu * Qt + w30;
        const double den_tot = q0 + di30 + dent;   // all terms positive
        const double dz0 = num * frcp(den_tot);

        // back-substitution
        const double rhsb0 = rhsb0_b + smu * rhsb0_c;
        const double rhsb1 = rhsb1_b + smu * rhsb1_c;
        const double rhsh0 = rhsh0_b + smu * rhsh0_c;
        const double rhsh1 = rhsh1_b + smu * rhsh1_c;
        const double dzb0 = (rhsb0 - di1_0 * dz0) * rcb0;
        const double dzb1 = (rhsb1 - di1_1 * dz0) * rcb1;
        const double dzh0 = (rhsh0 + di2_0 * dz0) * rch0;
        const double dzh1 = (rhsh1 + di2_1 * dz0) * rch1;

        // ds = -r_prim - Gdz
        const double ds1_0 = dz0 + dzb0 - rp1_0, ds1_1 = dz0 + dzb1 - rp1_1;
        const double ds2_0 = dzh0 - dz0 - rp2_0, ds2_1 = dzh1 - dz0 - rp2_1;
        const double ds3b0 = dzb0 - rp3b0, ds3b1 = dzb1 - rp3b1;
        const double ds3h0 = dzh0 - rp3h0, ds3h1 = dzh1 - rp3h1;
        const double ds30 = dz0 - rp30;

        // dlam = -D*ds + smu/s - lam
        const double dl1_0 = smu * rs1_0 - l1_0 - di1_0 * ds1_0;
        const double dl1_1 = smu * rs1_1 - l1_1 - di1_1 * ds1_1;
        const double dl2_0 = smu * rs2_0 - l2_0 - di2_0 * ds2_0;
        const double dl2_1 = smu * rs2_1 - l2_1 - di2_1 * ds2_1;
        const double dl3b0 = smu * rs3b0 - l3b0 - di3b0 * ds3b0;
        const double dl3b1 = smu * rs3b1 - l3b1 - di3b1 * ds3b1;
        const double dl3h0 = smu * rs3h0 - l3h0 - di3h0 * ds3h0;
        const double dl3h1 = smu * rs3h1 - l3h1 - di3h1 * ds3h1;
        const double dl30 = smu * rs30 - l30 - di30 * ds30;

        // fraction-to-boundary in f32: mr = max(0, max(-dx * (1/x)))
        // (dx>0 gives negative term -> never wins the max; no branches)
        const float fs1_0 = (float)rs1_0, fs1_1 = (float)rs1_1;
        const float fs2_0 = (float)rs2_0, fs2_1 = (float)rs2_1;
        const float fs3b0 = (float)rs3b0, fs3b1 = (float)rs3b1;
        const float fs3h0 = (float)rs3h0, fs3h1 = (float)rs3h1;
        const float fs30 = (float)rs30;
        const float fl1_0 = frcpf((float)l1_0), fl1_1 = frcpf((float)l1_1);
        const float fl2_0 = frcpf((float)l2_0), fl2_1 = frcpf((float)l2_1);
        const float fl3b0 = frcpf((float)l3b0), fl3b1 = frcpf((float)l3b1);
        const float fl3h0 = frcpf((float)l3h0), fl3h1 = frcpf((float)l3h1);
        const float fl30 = frcpf((float)l30);

        float mr = 0.f;
        mr = fmaxf(mr, (float)(-ds1_0) * fs1_0);
        mr = fmaxf(mr, (float)(-ds1_1) * fs1_1);
        mr = fmaxf(mr, (float)(-ds2_0) * fs2_0);
        mr = fmaxf(mr, (float)(-ds2_1) * fs2_1);
        mr = fmaxf(mr, (float)(-ds3b0) * fs3b0);
        mr = fmaxf(mr, (float)(-ds3b1) * fs3b1);
        mr = fmaxf(mr, (float)(-ds3h0) * fs3h0);
        mr = fmaxf(mr, (float)(-ds3h1) * fs3h1);
        mr = fmaxf(mr, (float)(-ds30) * fs30);
        mr = fmaxf(mr, (float)(-dl1_0) * fl1_0);
        mr = fmaxf(mr, (float)(-dl1_1) * fl1_1);
        mr = fmaxf(mr, (float)(-dl2_0) * fl2_0);
        mr = fmaxf(mr, (float)(-dl2_1) * fl2_1);
        mr = fmaxf(mr, (float)(-dl3b0) * fl3b0);
        mr = fmaxf(mr, (float)(-dl3b1) * fl3b1);
        mr = fmaxf(mr, (float)(-dl3h0) * fl3h0);
        mr = fmaxf(mr, (float)(-dl3h1) * fl3h1);
        mr = fmaxf(mr, (float)(-dl30) * fl30);

#define MAX_STEP(C) mr = fmaxf(mr, dpp_f<C>(mr));
        MAX_STEP(0xB1) MAX_STEP(0x4E) MAX_STEP(0x141)
        MAX_STEP(0x140) MAX_STEP(0x142) MAX_STEP(0x143)
#undef MAX_STEP
        const float mrt = rdl63_f(mr);
        const float af = fminf(1.0f, 0.99f * frcpf(mrt));  // mrt==0 -> inf -> 1
        const double alpha = (double)af;

        // updates
        z0 += alpha * dz0;
        zb0 += alpha * dzb0; zb1 += alpha * dzb1;
        zh0 += alpha * dzh0; zh1 += alpha * dzh1;
        s1_0 += alpha * ds1_0; s1_1 += alpha * ds1_1;
        s2_0 += alpha * ds2_0; s2_1 += alpha * ds2_1;
        s3b0 += alpha * ds3b0; s3b1 += alpha * ds3b1;
        s3h0 += alpha * ds3h0; s3h1 += alpha * ds3h1;
        s30 += alpha * ds30;
        l1_0 += alpha * dl1_0; l1_1 += alpha * dl1_1;
        l2_0 += alpha * dl2_0; l2_1 += alpha * dl2_1;
        l3b0 += alpha * dl3b0; l3b1 += alpha * dl3b1;
        l3h0 += alpha * dl3h0; l3h1 += alpha * dl3h1;
        l30 += alpha * dl30;
    }

    if (lane == 0) out[b] = (float)z0;
}

extern "C" void kernel_launch(void* const* d_in, const int* in_sizes, int n_in,
                              void* d_out, int out_size, void* d_ws, size_t ws_size,
                              hipStream_t stream) {
    const float* y  = (const float*)d_in[0];
    const float* Qd = (const float*)d_in[1];
    const float* pv = (const float*)d_in[2];
    // d_in[3] = G (implicit structure, unused)
    const float* h  = (const float*)d_in[4];
    float* out = (float*)d_out;

    newsvendor_pdip<<<NB, 64, 0, stream>>>(y, Qd, pv, h, out);
}

// Round 5
// 19.651 us; speedup vs baseline: 3.5507x; 1.3525x over previous
//
#include <hip/hip_runtime.h>

#define KQ 128
#define NB 128
#define ITERS 25
#define SMU_SCALE (0.1f / 385.0f)   // SIGMA / M

__device__ __forceinline__ float frcpf(float x) {
#if __has_builtin(__builtin_amdgcn_rcpf)
    return __builtin_amdgcn_rcpf(x);
#else
    return 1.0f / x;
#endif
}

// DPP cross-lane move (zero-fill OOB). Full 64-lane reduce sequence:
// 0xB1 quad xor1, 0x4E quad xor2, 0x141 row_half_mirror, 0x140 row_mirror,
// 0x142 row_bcast15, 0x143 row_bcast31 -> result valid in lane 63.
template <int CTRL>
__device__ __forceinline__ float dpp_f(float v) {
    union { float f; int i; } u, r;
    u.f = v;
    r.i = __builtin_amdgcn_update_dpp(0, u.i, CTRL, 0xf, 0xf, true);
    return r.f;
}
__device__ __forceinline__ float rdl63_f(float v) {
    union { float f; int i; } u, r;
    u.f = v;
    r.i = __builtin_amdgcn_readlane(u.i, 63);
    return r.f;
}

// One 64-lane wave per batch element; lane owns quantile indices (lane, lane+64).
// Fully f32 (matches the f32 jax reference's own arithmetic regime).
// Reduced KKT (diag(q)+G'DG) is an arrow matrix solved exactly via Schur
// complement on the (0,0) entry; denominator in cancellation-free all-positive
// form q0 + d30 + sum d*(q+d3)/c  (this structure, not precision, is what
// prevents the R0 NaN blowup).
__global__ __launch_bounds__(64) void newsvendor_pdip(
    const float* __restrict__ y,   // (B,K)
    const float* __restrict__ Qd,  // (N)
    const float* __restrict__ pv,  // (N)
    const float* __restrict__ h,   // (M)
    float* __restrict__ out)       // (B)
{
    const int b = blockIdx.x;
    const int lane = threadIdx.x;
    const int i0 = lane, i1 = lane + 64;

    const float y0 = y[b * KQ + i0], y1 = y[b * KQ + i1];
    const float d0 = -h[i0], d1v = -h[i1];        // h[0:K] = -d
    const float q0 = Qd[0], p0c = pv[0];
    const float qb0 = Qd[1 + i0] * y0,      qb1 = Qd[1 + i1] * y1;
    const float qh0 = Qd[1 + KQ + i0] * y0, qh1 = Qd[1 + KQ + i1] * y1;
    const float pb0 = pv[1 + i0] * y0,      pb1 = pv[1 + i1] * y1;
    const float ph0 = pv[1 + KQ + i0] * y0, ph1 = pv[1 + KQ + i1] * y1;

    // state
    float z0 = 0, zb0 = 0, zb1 = 0, zh0 = 0, zh1 = 0;
    float s1_0 = 1, s1_1 = 1, s2_0 = 1, s2_1 = 1;
    float s3b0 = 1, s3b1 = 1, s3h0 = 1, s3h1 = 1, s30 = 1;
    float l1_0 = 1, l1_1 = 1, l2_0 = 1, l2_1 = 1;
    float l3b0 = 1, l3b1 = 1, l3h0 = 1, l3h1 = 1, l30 = 1;

#pragma unroll 1
    for (int it = 0; it < ITERS; ++it) {
        // reciprocals (v_rcp_f32, ~1 ulp — all independent, pipelined)
        const float rs1_0 = frcpf(s1_0), rs1_1 = frcpf(s1_1);
        const float rs2_0 = frcpf(s2_0), rs2_1 = frcpf(s2_1);
        const float rs3b0 = frcpf(s3b0), rs3b1 = frcpf(s3b1);
        const float rs3h0 = frcpf(s3h0), rs3h1 = frcpf(s3h1);
        const float rs30 = frcpf(s30);
        const float rl1_0 = frcpf(l1_0), rl1_1 = frcpf(l1_1);
        const float rl2_0 = frcpf(l2_0), rl2_1 = frcpf(l2_1);
        const float rl3b0 = frcpf(l3b0), rl3b1 = frcpf(l3b1);
        const float rl3h0 = frcpf(l3h0), rl3h1 = frcpf(l3h1);
        const float rl30 = frcpf(l30);

        // D = lam/s
        const float di1_0 = l1_0 * rs1_0, di1_1 = l1_1 * rs1_1;
        const float di2_0 = l2_0 * rs2_0, di2_1 = l2_1 * rs2_1;
        const float di3b0 = l3b0 * rs3b0, di3b1 = l3b1 * rs3b1;
        const float di3h0 = l3h0 * rs3h0, di3h1 = l3h1 * rs3h1;
        const float di30 = l30 * rs30;

        // r_prim = Gz + s - h
        const float rp1_0 = s1_0 + d0 - z0 - zb0;
        const float rp1_1 = s1_1 + d1v - z0 - zb1;
        const float rp2_0 = s2_0 - d0 + z0 - zh0;
        const float rp2_1 = s2_1 - d1v + z0 - zh1;
        const float rp3b0 = s3b0 - zb0, rp3b1 = s3b1 - zb1;
        const float rp3h0 = s3h0 - zh0, rp3h1 = s3h1 - zh1;
        const float rp30 = s30 - z0;

        // w-base = D*r_prim  (w = wb + smu/s, linear in smu)
        const float wb1_0 = di1_0 * rp1_0, wb1_1 = di1_1 * rp1_1;
        const float wb2_0 = di2_0 * rp2_0, wb2_1 = di2_1 * rp2_1;

        // rhs split base/coef
        const float rhsb0_b = wb1_0 + di3b0 * rp3b0 - (qb0 * zb0 + pb0);
        const float rhsb1_b = wb1_1 + di3b1 * rp3b1 - (qb1 * zb1 + pb1);
        const float rhsh0_b = wb2_0 + di3h0 * rp3h0 - (qh0 * zh0 + ph0);
        const float rhsh1_b = wb2_1 + di3h1 * rp3h1 - (qh1 * zh1 + ph1);
        const float rhsb0_c = rs1_0 + rs3b0, rhsb1_c = rs1_1 + rs3b1;
        const float rhsh0_c = rs2_0 + rs3h0, rhsh1_c = rs2_1 + rs3h1;

        // arrow diagonal c = t + d1/d2, t = q + d3 (cancel-free den pieces)
        const float tb0 = qb0 + di3b0, tb1 = qb1 + di3b1;
        const float th0 = qh0 + di3h0, th1 = qh1 + di3h1;
        const float cb0 = tb0 + di1_0, cb1 = tb1 + di1_1;
        const float ch0 = th0 + di2_0, ch1 = th1 + di2_1;
        const float rcb0 = frcpf(cb0), rcb1 = frcpf(cb1);
        const float rch0 = frcpf(ch0), rch1 = frcpf(ch1);
        const float eb0 = di1_0 * rcb0, eb1 = di1_1 * rcb1;
        const float eh0 = di2_0 * rch0, eh1 = di2_1 * rch1;

        // fused reduction payloads:
        // P = (w@G)_0 base + sbr base ; Q = same, smu coefs ; den = Schur sum
        float P = wb2_0 + wb2_1 - wb1_0 - wb1_1
                + eb0 * rhsb0_b + eb1 * rhsb1_b - eh0 * rhsh0_b - eh1 * rhsh1_b;
        float Q = rs2_0 + rs2_1 - rs1_0 - rs1_1
                + eb0 * rhsb0_c + eb1 * rhsb1_c - eh0 * rhsh0_c - eh1 * rhsh1_c;
        float den = eb0 * tb0 + eb1 * tb1 + eh0 * th0 + eh1 * th1;
        float mus = s1_0 * l1_0 + s1_1 * l1_1 + s2_0 * l2_0 + s2_1 * l2_1
                  + s3b0 * l3b0 + s3b1 * l3b1 + s3h0 * l3h0 + s3h1 * l3h1;

#define SUM_STEP(C) \
        P += dpp_f<C>(P); Q += dpp_f<C>(Q); den += dpp_f<C>(den); mus += dpp_f<C>(mus);
        SUM_STEP(0xB1) SUM_STEP(0x4E) SUM_STEP(0x141)
        SUM_STEP(0x140) SUM_STEP(0x142) SUM_STEP(0x143)
#undef SUM_STEP
        const float Pt = rdl63_f(P);
        const float Qt = rdl63_f(Q);
        const float dent = rdl63_f(den);
        const float must = rdl63_f(mus) + s30 * l30;

        // wave-uniform scalar pieces
        const float smu = SMU_SCALE * must;
        const float w30 = di30 * rp30 + smu * rs30;
        const float num = w30 - (q0 * z0 + p0c) - Pt - smu * Qt;
        const float den_tot = q0 + di30 + dent;   // all terms positive
        const float dz0 = num * frcpf(den_tot);

        // back-substitution
        const float rhsb0 = rhsb0_b + smu * rhsb0_c;
        const float rhsb1 = rhsb1_b + smu * rhsb1_c;
        const float rhsh0 = rhsh0_b + smu * rhsh0_c;
        const float rhsh1 = rhsh1_b + smu * rhsh1_c;
        const float dzb0 = (rhsb0 - di1_0 * dz0) * rcb0;
        const float dzb1 = (rhsb1 - di1_1 * dz0) * rcb1;
        const float dzh0 = (rhsh0 + di2_0 * dz0) * rch0;
        const float dzh1 = (rhsh1 + di2_1 * dz0) * rch1;

        // ds = -r_prim - Gdz
        const float ds1_0 = dz0 + dzb0 - rp1_0, ds1_1 = dz0 + dzb1 - rp1_1;
        const float ds2_0 = dzh0 - dz0 - rp2_0, ds2_1 = dzh1 - dz0 - rp2_1;
        const float ds3b0 = dzb0 - rp3b0, ds3b1 = dzb1 - rp3b1;
        const float ds3h0 = dzh0 - rp3h0, ds3h1 = dzh1 - rp3h1;
        const float ds30 = dz0 - rp30;

        // dlam = -D*ds + smu/s - lam
        const float dl1_0 = smu * rs1_0 - l1_0 - di1_0 * ds1_0;
        const float dl1_1 = smu * rs1_1 - l1_1 - di1_1 * ds1_1;
        const float dl2_0 = smu * rs2_0 - l2_0 - di2_0 * ds2_0;
        const float dl2_1 = smu * rs2_1 - l2_1 - di2_1 * ds2_1;
        const float dl3b0 = smu * rs3b0 - l3b0 - di3b0 * ds3b0;
        const float dl3b1 = smu * rs3b1 - l3b1 - di3b1 * ds3b1;
        const float dl3h0 = smu * rs3h0 - l3h0 - di3h0 * ds3h0;
        const float dl3h1 = smu * rs3h1 - l3h1 - di3h1 * ds3h1;
        const float dl30 = smu * rs30 - l30 - di30 * ds30;

        // fraction-to-boundary: mr = max(0, max(-dx/x)); terms with dx>0 are
        // negative and never win the max. v_max3-friendly tree, depth 3.
        const float t00 = -ds1_0 * rs1_0,  t01 = -ds1_1 * rs1_1;
        const float t02 = -ds2_0 * rs2_0,  t03 = -ds2_1 * rs2_1;
        const float t04 = -ds3b0 * rs3b0,  t05 = -ds3b1 * rs3b1;
        const float t06 = -ds3h0 * rs3h0,  t07 = -ds3h1 * rs3h1;
        const float t08 = -ds30 * rs30,    t09 = -dl30 * rl30;
        const float t10 = -dl1_0 * rl1_0,  t11 = -dl1_1 * rl1_1;
        const float t12 = -dl2_0 * rl2_0,  t13 = -dl2_1 * rl2_1;
        const float t14 = -dl3b0 * rl3b0,  t15 = -dl3b1 * rl3b1;
        const float t16 = -dl3h0 * rl3h0,  t17 = -dl3h1 * rl3h1;
        const float g0 = fmaxf(fmaxf(t00, t01), t02);
        const float g1 = fmaxf(fmaxf(t03, t04), t05);
        const float g2 = fmaxf(fmaxf(t06, t07), t08);
        const float g3 = fmaxf(fmaxf(t09, t10), t11);
        const float g4 = fmaxf(fmaxf(t12, t13), t14);
        const float g5 = fmaxf(fmaxf(t15, t16), t17);
        const float h0 = fmaxf(fmaxf(g0, g1), g2);
        const float h1 = fmaxf(fmaxf(g3, g4), g5);
        float mr = fmaxf(fmaxf(h0, h1), 0.0f);

#define MAX_STEP(C) mr = fmaxf(mr, dpp_f<C>(mr));
        MAX_STEP(0xB1) MAX_STEP(0x4E) MAX_STEP(0x141)
        MAX_STEP(0x140) MAX_STEP(0x142) MAX_STEP(0x143)
#undef MAX_STEP
        const float mrt = rdl63_f(mr);
        const float af = fminf(1.0f, 0.99f * frcpf(mrt));  // mrt==0 -> inf -> 1

        // updates
        z0 = fmaf(af, dz0, z0);
        zb0 = fmaf(af, dzb0, zb0); zb1 = fmaf(af, dzb1, zb1);
        zh0 = fmaf(af, dzh0, zh0); zh1 = fmaf(af, dzh1, zh1);
        s1_0 = fmaf(af, ds1_0, s1_0); s1_1 = fmaf(af, ds1_1, s1_1);
        s2_0 = fmaf(af, ds2_0, s2_0); s2_1 = fmaf(af, ds2_1, s2_1);
        s3b0 = fmaf(af, ds3b0, s3b0); s3b1 = fmaf(af, ds3b1, s3b1);
        s3h0 = fmaf(af, ds3h0, s3h0); s3h1 = fmaf(af, ds3h1, s3h1);
        s30 = fmaf(af, ds30, s30);
        l1_0 = fmaf(af, dl1_0, l1_0); l1_1 = fmaf(af, dl1_1, l1_1);
        l2_0 = fmaf(af, dl2_0, l2_0); l2_1 = fmaf(af, dl2_1, l2_1);
        l3b0 = fmaf(af, dl3b0, l3b0); l3b1 = fmaf(af, dl3b1, l3b1);
        l3h0 = fmaf(af, dl3h0, l3h0); l3h1 = fmaf(af, dl3h1, l3h1);
        l30 = fmaf(af, dl30, l30);
    }

    if (lane == 0) out[b] = z0;
}

extern "C" void kernel_launch(void* const* d_in, const int* in_sizes, int n_in,
                              void* d_out, int out_size, void* d_ws, size_t ws_size,
                              hipStream_t stream) {
    const float* y  = (const float*)d_in[0];
    const float* Qd = (const float*)d_in[1];
    const float* pv = (const float*)d_in[2];
    // d_in[3] = G (implicit structure, unused)
    const float* h  = (const float*)d_in[4];
    float* out = (float*)d_out;

    newsvendor_pdip<<<NB, 64, 0, stream>>>(y, Qd, pv, h, out);
}

// Round 6
// 17.695 us; speedup vs baseline: 3.9430x; 1.1105x over previous
//
#include <hip/hip_runtime.h>

#define KQ 128
#define NB 128
#define ITERS 25
#define SMU_SCALE (0.1f / 385.0f)   // SIGMA / M

typedef float v2f __attribute__((ext_vector_type(2)));

__device__ __forceinline__ float frcpf(float x) {
#if __has_builtin(__builtin_amdgcn_rcpf)
    return __builtin_amdgcn_rcpf(x);
#else
    return 1.0f / x;
#endif
}
__device__ __forceinline__ v2f rcp2(v2f x) {
    v2f r; r.x = frcpf(x.x); r.y = frcpf(x.y); return r;
}
__device__ __forceinline__ v2f splat(float x) { v2f r; r.x = x; r.y = x; return r; }

// DPP cross-lane move (zero-fill OOB). Full 64-lane reduce sequence:
// 0xB1 quad xor1, 0x4E quad xor2, 0x141 row_half_mirror, 0x140 row_mirror,
// 0x142 row_bcast15, 0x143 row_bcast31 -> result valid in lane 63.
template <int CTRL>
__device__ __forceinline__ float dpp_f(float v) {
    union { float f; int i; } u, r;
    u.f = v;
    r.i = __builtin_amdgcn_update_dpp(0, u.i, CTRL, 0xf, 0xf, true);
    return r.f;
}
template <int CTRL>
__device__ __forceinline__ v2f dpp_v2(v2f v) {
    union { v2f v; int i[2]; } u, r;
    u.v = v;
    r.i[0] = __builtin_amdgcn_update_dpp(0, u.i[0], CTRL, 0xf, 0xf, true);
    r.i[1] = __builtin_amdgcn_update_dpp(0, u.i[1], CTRL, 0xf, 0xf, true);
    return r.v;
}
__device__ __forceinline__ float rdl63_f(float v) {
    union { float f; int i; } u, r;
    u.f = v;
    r.i = __builtin_amdgcn_readlane(u.i, 63);
    return r.f;
}

// One 64-lane wave per batch element; lane owns quantile indices (lane, lane+64),
// held as packed v2f pairs so the backend emits v_pk_{fma,mul,add}_f32 (VOP3P)
// — ~halves issued VALU instructions in this latency-bound, 1-wave/SIMD regime.
// Reduced KKT (diag(q)+G'DG) is an arrow matrix solved exactly via Schur
// complement on the (0,0) entry; denominator in cancellation-free all-positive
// form q0 + d30 + sum d*(q+d3)/c.
__global__ __launch_bounds__(64) void newsvendor_pdip(
    const float* __restrict__ y,   // (B,K)
    const float* __restrict__ Qd,  // (N)
    const float* __restrict__ pv,  // (N)
    const float* __restrict__ h,   // (M)
    float* __restrict__ out)       // (B)
{
    const int b = blockIdx.x;
    const int lane = threadIdx.x;
    const int i0 = lane, i1 = lane + 64;

    v2f yv;  yv.x = y[b * KQ + i0];  yv.y = y[b * KQ + i1];
    v2f dv;  dv.x = -h[i0];          dv.y = -h[i1];     // h[0:K] = -d
    const float q0 = Qd[0], p0c = pv[0];
    v2f qb;  qb.x = Qd[1 + i0];       qb.y = Qd[1 + i1];       qb *= yv;
    v2f qh;  qh.x = Qd[1 + KQ + i0];  qh.y = Qd[1 + KQ + i1];  qh *= yv;
    v2f pb;  pb.x = pv[1 + i0];       pb.y = pv[1 + i1];       pb *= yv;
    v2f ph;  ph.x = pv[1 + KQ + i0];  ph.y = pv[1 + KQ + i1];  ph *= yv;

    // state (packed pairs + uniform scalar block)
    float z0 = 0, s30 = 1, l30 = 1;
    v2f zb = splat(0.f), zh = splat(0.f);
    v2f s1 = splat(1.f), s2 = splat(1.f), s3b = splat(1.f), s3h = splat(1.f);
    v2f l1 = splat(1.f), l2 = splat(1.f), l3b = splat(1.f), l3h = splat(1.f);

#pragma unroll 1
    for (int it = 0; it < ITERS; ++it) {
        // reciprocals (v_rcp_f32, ~1 ulp; all independent)
        const v2f rs1 = rcp2(s1), rs2 = rcp2(s2);
        const v2f rs3b = rcp2(s3b), rs3h = rcp2(s3h);
        const float rs30 = frcpf(s30);
        const v2f rl1 = rcp2(l1), rl2 = rcp2(l2);
        const v2f rl3b = rcp2(l3b), rl3h = rcp2(l3h);
        const float rl30 = frcpf(l30);

        // D = lam/s
        const v2f di1 = l1 * rs1, di2 = l2 * rs2;
        const v2f di3b = l3b * rs3b, di3h = l3h * rs3h;
        const float di30 = l30 * rs30;

        // r_prim = Gz + s - h
        const v2f z0v = splat(z0);
        const v2f rp1 = s1 + dv - z0v - zb;
        const v2f rp2 = s2 - dv + z0v - zh;
        const v2f rp3b = s3b - zb, rp3h = s3h - zh;
        const float rp30 = s30 - z0;

        // w-base = D*r_prim  (w = wb + smu/s, linear in smu)
        const v2f wb1 = di1 * rp1, wb2 = di2 * rp2;

        // rhs split base/coef
        const v2f rhsb_b = wb1 + di3b * rp3b - (qb * zb + pb);
        const v2f rhsh_b = wb2 + di3h * rp3h - (qh * zh + ph);
        const v2f rhsb_c = rs1 + rs3b, rhsh_c = rs2 + rs3h;

        // arrow diagonal c = t + d, t = q + d3 (cancel-free den pieces)
        const v2f tb = qb + di3b, th = qh + di3h;
        const v2f cb = tb + di1, ch = th + di2;
        const v2f rcb = rcp2(cb), rch = rcp2(ch);
        const v2f eb = di1 * rcb, eh = di2 * rch;

        // fused reduction payloads (packed partials -> horizontal -> packed DPP)
        const v2f Pp = wb2 - wb1 + eb * rhsb_b - eh * rhsh_b;
        const v2f Qp = rs2 - rs1 + eb * rhsb_c - eh * rhsh_c;
        const v2f denp = eb * tb + eh * th;
        const v2f musp = s1 * l1 + s2 * l2 + s3b * l3b + s3h * l3h;

        v2f PQ;  PQ.x = Pp.x + Pp.y;    PQ.y = Qp.x + Qp.y;
        v2f DM;  DM.x = denp.x + denp.y; DM.y = musp.x + musp.y;
#define SUM_STEP(C) PQ += dpp_v2<C>(PQ); DM += dpp_v2<C>(DM);
        SUM_STEP(0xB1) SUM_STEP(0x4E) SUM_STEP(0x141)
        SUM_STEP(0x140) SUM_STEP(0x142) SUM_STEP(0x143)
#undef SUM_STEP
        const float Pt = rdl63_f(PQ.x);
        const float Qt = rdl63_f(PQ.y);
        const float dent = rdl63_f(DM.x);
        const float must = rdl63_f(DM.y) + s30 * l30;

        // wave-uniform scalar pieces
        const float smu = SMU_SCALE * must;
        const float w30 = di30 * rp30 + smu * rs30;
        const float num = w30 - (q0 * z0 + p0c) - Pt - smu * Qt;
        const float den_tot = q0 + di30 + dent;   // all terms positive
        const float dz0 = num * frcpf(den_tot);

        // back-substitution
        const v2f smuv = splat(smu);
        const v2f dz0v = splat(dz0);
        const v2f rhsb = rhsb_b + smuv * rhsb_c;
        const v2f rhsh = rhsh_b + smuv * rhsh_c;
        const v2f dzb = (rhsb - di1 * dz0v) * rcb;
        const v2f dzh = (rhsh + di2 * dz0v) * rch;

        // ds = -r_prim - Gdz
        const v2f ds1 = dz0v + dzb - rp1;
        const v2f ds2 = dzh - dz0v - rp2;
        const v2f ds3b = dzb - rp3b, ds3h = dzh - rp3h;
        const float ds30 = dz0 - rp30;

        // dlam = -D*ds + smu/s - lam
        const v2f dl1 = smuv * rs1 - l1 - di1 * ds1;
        const v2f dl2 = smuv * rs2 - l2 - di2 * ds2;
        const v2f dl3b = smuv * rs3b - l3b - di3b * ds3b;
        const v2f dl3h = smuv * rs3h - l3h - di3h * ds3h;
        const float dl30 = smu * rs30 - l30 - di30 * ds30;

        // fraction-to-boundary: mr = max(0, max(-dx/x)); dx>0 terms are
        // negative and never win the max.
        const v2f u1 = -ds1 * rs1,  u2 = -ds2 * rs2;
        const v2f u3 = -ds3b * rs3b, u4 = -ds3h * rs3h;
        const v2f u5 = -dl1 * rl1,  u6 = -dl2 * rl2;
        const v2f u7 = -dl3b * rl3b, u8 = -dl3h * rl3h;
        const float m1 = fmaxf(u1.x, u1.y), m2 = fmaxf(u2.x, u2.y);
        const float m3 = fmaxf(u3.x, u3.y), m4 = fmaxf(u4.x, u4.y);
        const float m5 = fmaxf(u5.x, u5.y), m6 = fmaxf(u6.x, u6.y);
        const float m7 = fmaxf(u7.x, u7.y), m8 = fmaxf(u8.x, u8.y);
        const float t08 = -ds30 * rs30, t09 = -dl30 * rl30;
        const float g0 = fmaxf(fmaxf(m1, m2), m3);
        const float g1 = fmaxf(fmaxf(m4, m5), m6);
        const float g2 = fmaxf(fmaxf(m7, m8), t08);
        float mr = fmaxf(fmaxf(fmaxf(g0, g1), g2), fmaxf(t09, 0.0f));

#define MAX_STEP(C) mr = fmaxf(mr, dpp_f<C>(mr));
        MAX_STEP(0xB1) MAX_STEP(0x4E) MAX_STEP(0x141)
        MAX_STEP(0x140) MAX_STEP(0x142) MAX_STEP(0x143)
#undef MAX_STEP
        const float mrt = rdl63_f(mr);
        const float af = fminf(1.0f, 0.99f * frcpf(mrt));  // mrt==0 -> inf -> 1
        const v2f afv = splat(af);

        // updates (pk_fma)
        z0 = fmaf(af, dz0, z0);
        zb += afv * dzb;   zh += afv * dzh;
        s1 += afv * ds1;   s2 += afv * ds2;
        s3b += afv * ds3b; s3h += afv * ds3h;
        s30 = fmaf(af, ds30, s30);
        l1 += afv * dl1;   l2 += afv * dl2;
        l3b += afv * dl3b; l3h += afv * dl3h;
        l30 = fmaf(af, dl30, l30);
    }

    if (lane == 0) out[b] = z0;
}

extern "C" void kernel_launch(void* const* d_in, const int* in_sizes, int n_in,
                              void* d_out, int out_size, void* d_ws, size_t ws_size,
                              hipStream_t stream) {
    const float* y  = (const float*)d_in[0];
    const float* Qd = (const float*)d_in[1];
    const float* pv = (const float*)d_in[2];
    // d_in[3] = G (implicit structure, unused)
    const float* h  = (const float*)d_in[4];
    float* out = (float*)d_out;

    newsvendor_pdip<<<NB, 64, 0, stream>>>(y, Qd, pv, h, out);
}

// Round 7
// 9.268 us; speedup vs baseline: 7.5286x; 1.9093x over previous
//
#include <hip/hip_runtime.h>

#define KQ 128
#define NB 128

// ---------- f64 DPP cross-lane helpers ----------
template <int CTRL, int RMASK, bool BOUND>
__device__ __forceinline__ double dpp_mv_d(double v) {
    union { double d; int i[2]; } u, r;
    u.d = v;
    r.i[0] = __builtin_amdgcn_update_dpp(0, u.i[0], CTRL, RMASK, 0xf, BOUND);
    r.i[1] = __builtin_amdgcn_update_dpp(0, u.i[1], CTRL, RMASK, 0xf, BOUND);
    return r.d;
}
__device__ __forceinline__ double rdl63_d(double v) {
    union { double d; int i[2]; } u, r;
    u.d = v;
    r.i[0] = __builtin_amdgcn_readlane(u.i[0], 63);
    r.i[1] = __builtin_amdgcn_readlane(u.i[1], 63);
    return r.d;
}

// inclusive 64-lane scan (Hillis-Steele: row_shr 1/2/4/8 then row_bcast15/31)
__device__ __forceinline__ void wscan2_d(double& a, double& b) {
    a += dpp_mv_d<0x111, 0xf, true>(a);   b += dpp_mv_d<0x111, 0xf, true>(b);
    a += dpp_mv_d<0x112, 0xf, true>(a);   b += dpp_mv_d<0x112, 0xf, true>(b);
    a += dpp_mv_d<0x114, 0xf, true>(a);   b += dpp_mv_d<0x114, 0xf, true>(b);
    a += dpp_mv_d<0x118, 0xf, true>(a);   b += dpp_mv_d<0x118, 0xf, true>(b);
    a += dpp_mv_d<0x142, 0xa, false>(a);  b += dpp_mv_d<0x142, 0xa, false>(b);
    a += dpp_mv_d<0x143, 0xc, false>(a);  b += dpp_mv_d<0x143, 0xc, false>(b);
}

__device__ __forceinline__ double wmax_d(double v) {
    v = fmax(v, dpp_mv_d<0xB1,  0xf, true>(v));
    v = fmax(v, dpp_mv_d<0x4E,  0xf, true>(v));
    v = fmax(v, dpp_mv_d<0x141, 0xf, true>(v));
    v = fmax(v, dpp_mv_d<0x140, 0xf, true>(v));
    v = fmax(v, dpp_mv_d<0x142, 0xf, true>(v));
    v = fmax(v, dpp_mv_d<0x143, 0xf, true>(v));
    return rdl63_d(v);
}

// Exact 1-D solve. For fixed z0 the QP is separable: b_i's objective
// 0.5*qb*b^2 + pb*b has qb,pb>0 -> increasing on the feasible set
// {b >= max(0, d_i - z0)} -> b_i* = max(0, d_i - z0); h_i* = max(0, z0 - d_i).
// So z0* minimizes the convex piecewise-quadratic
//   F(z) = 0.5*Cq*z^2 + Cl*z
//        + sum_i y_i [0.5*Bq*max(0,d_i-z)^2 + Bl*max(0,d_i-z)
//                   + 0.5*Hq*max(0,z-d_i)^2 + Hl*max(0,z-d_i)],  z >= 0.
// F'(z) is piecewise-linear increasing with breakpoints at d_i = 1..K.
// On segment k (z in [k, k+1], below-set = quantiles i<k):
//   b_k = Cq + Bq*(T0-PS0) + Hq*PS0
//   a_k = Cl - Bq*(T1-PS1) - Bl*(T0-PS0) - Hq*PS1 + Hl*PS0
// where PS = prefix sums of (y, y*d) below k, T = totals. Root of a+b*z,
// clamped per segment; kink roots handled by the F'(hi)<0 -> hi rule;
// z*=0 handled by the max-with-0 init. F'(K) > 0 always (K*T0 > T1), so
// the root is always < K and segment K need not be represented.
__global__ __launch_bounds__(64) void newsvendor_analytic(
    const float* __restrict__ y,   // (B,K)
    const float* __restrict__ Qd,  // (N): [Cq, Bq*K, Hq*K]
    const float* __restrict__ pv,  // (N): [Cl, Bl*K, Hl*K]
    const float* __restrict__ h,   // (M): h[0:K] = -d
    float* __restrict__ out)       // (B)
{
    const int b = blockIdx.x;
    const int lane = threadIdx.x;
    const int j0 = 2 * lane, j1 = 2 * lane + 1;

    const double y0 = (double)y[b * KQ + j0];
    const double y1 = (double)y[b * KQ + j1];
    const double d0 = -(double)h[j0];
    const double d1 = -(double)h[j1];

    const double Cq = (double)Qd[0], Bq = (double)Qd[1], Hq = (double)Qd[1 + KQ];
    const double Cl = (double)pv[0], Bl = (double)pv[1], Hl = (double)pv[1 + KQ];

    // inclusive prefix over quantiles (pairs per lane), then totals
    const double pair0 = y0 + y1;
    const double pair1 = y0 * d0 + y1 * d1;
    double is0 = pair0, is1 = pair1;
    wscan2_d(is0, is1);
    const double T0 = rdl63_d(is0);
    const double T1 = rdl63_d(is1);
    const double e0 = is0 - pair0;   // exclusive prefix: sum over i < j0
    const double e1 = is1 - pair1;

    double cand = 0.0;
#pragma unroll
    for (int t = 0; t < 2; ++t) {
        const double kk  = (t == 0) ? (double)j0 : (double)j1;
        const double PS0 = (t == 0) ? e0 : e0 + y0;
        const double PS1 = (t == 0) ? e1 : e1 + y0 * d0;
        const double S0a = T0 - PS0, S1a = T1 - PS1;
        const double bk = Cq + Bq * S0a + Hq * PS0;
        const double ak = Cl - Bq * S1a - Bl * S0a - Hq * PS1 + Hl * PS0;
        const double zc = -ak / bk;
        const double lo = kk, hi = kk + 1.0;
        const double c = (zc >= lo && zc <= hi) ? zc
                       : ((ak + bk * hi < 0.0) ? hi : 0.0);
        cand = fmax(cand, c);
    }

    const double zstar = wmax_d(cand);
    if (lane == 0) out[b] = (float)zstar;
}

extern "C" void kernel_launch(void* const* d_in, const int* in_sizes, int n_in,
                              void* d_out, int out_size, void* d_ws, size_t ws_size,
                              hipStream_t stream) {
    const float* y  = (const float*)d_in[0];
    const float* Qd = (const float*)d_in[1];
    const float* pv = (const float*)d_in[2];
    // d_in[3] = G (implicit structure, unused)
    const float* h  = (const float*)d_in[4];
    float* out = (float*)d_out;

    newsvendor_analytic<<<NB, 64, 0, stream>>>(y, Qd, pv, h, out);
}